// Round 5
// baseline (314.680 us; speedup 1.0000x reference)
//
#include <hip/hip_runtime.h>

// SAGEConv — fp8-gather + fused aggregate/GEMM, fixed-capacity buckets.
// R11 post-mortem: fusing prep into 1 dispatch saved only 6us -> launch
// overhead NOT the invisible cost; k_prep sits just under the 61.9us top-5
// cut. k_agg 62us latency-bound: Phase B = 8 dependent ~600ns waits/wave
// with ~40ns VALU each -> 24 waves x 40/640 = 1.5/4 SIMDs = VALUBusy 30%.
// R12: Phase B restructure: (a) 8-lane groups (64 groups = 64 nodes, no
// serial node loop), uint4 16B loads (full 128B row per group-load),
// 8-deep chains -> waits/wave 8 -> ~2; (b) floatx2 (pk_add) accumulators;
// (c) LDS 42.5->39.0KB (CAPB 1536, XST 258 = +1-pad conflict-free) ->
// 4 blocks/CU possible. Predict k_agg ~40-45us, total ~160.

constexpr int NN = 100000;
constexpr int NE = 1600000;
constexpr int D  = 128;
constexpr int BK = 64;                      // nodes per bucket
constexpr int NB = (NN + BK - 1) / BK;      // 1563 buckets
constexpr int PB = 8192;                    // edges per partition block
constexpr int CAPB = 1536;                  // fixed bucket capacity (mean 1024, sd 32 -> +16sigma)
constexpr int XST = 258;                    // Xs row stride (shorts): 516B = 129 banks -> +1 pad
constexpr int PADI = 32;                    // ints per bucket counter slot (128B line)
constexpr int PART_BLOCKS = (NE + PB - 1) / PB;   // 196
constexpr int WPK_BLOCKS  = 16;
constexpr int CVT_BLOCKS  = NN * D / 8 / 256;     // 6250

typedef __attribute__((ext_vector_type(8))) short short8;   // 8 bf16 (4 VGPR)
typedef __attribute__((ext_vector_type(4))) float floatx4;  // MFMA C/D
typedef __attribute__((ext_vector_type(2))) float floatx2;

static __device__ __forceinline__ unsigned short f2bf(float f) {
    unsigned u = __float_as_uint(f);
    unsigned r = ((u >> 16) & 1u) + 0x7fffu;
    return (unsigned short)((u + r) >> 16);
}

// ---------------------------------------------------------------------------
// Fused prep: blocks [0,196) partition edges; [196,212) pack Wcat;
// [212,6462) h fp32 -> fp8. Part blocks first (long pole starts first).
// ---------------------------------------------------------------------------
__global__ __launch_bounds__(256) void k_prep(
    const float* __restrict__ h, const float* __restrict__ Wself,
    const float* __restrict__ Wneigh, const int* __restrict__ src,
    const int* __restrict__ dst, uint2* __restrict__ hf8,
    unsigned short* __restrict__ Wp, int* __restrict__ bcursor,
    unsigned* __restrict__ packed)
{
    const int t = threadIdx.x;
    if (blockIdx.x < PART_BLOCKS) {
        // ---- edge partition into fixed-capacity buckets ----
        __shared__ int lh[NB];
        const int e0 = blockIdx.x * PB;
        for (int i = t; i < NB; i += 256) lh[i] = 0;
        __syncthreads();

        int myd[32], msrc[32];
#pragma unroll
        for (int j = 0; j < 32; ++j) {
            int e = e0 + j * 256 + t;
            myd[j] = (e < NE) ? dst[e] : -1;
        }
#pragma unroll
        for (int j = 0; j < 32; ++j) {
            int e = e0 + j * 256 + t;
            msrc[j] = (e < NE) ? src[e] : 0;
        }
#pragma unroll
        for (int j = 0; j < 32; ++j)
            if (myd[j] >= 0) atomicAdd(&lh[myd[j] >> 6], 1);
        __syncthreads();
        for (int i = t; i < NB; i += 256) {
            int c = lh[i];
            if (c) lh[i] = atomicAdd(&bcursor[(size_t)i * PADI], c);
        }
        __syncthreads();
#pragma unroll
        for (int j = 0; j < 32; ++j) {
            if (myd[j] >= 0) {
                int b = myd[j] >> 6;
                int pos = atomicAdd(&lh[b], 1);        // within-bucket rank
                if (pos < CAPB)
                    packed[(size_t)b * CAPB + pos] =
                        (unsigned)msrc[j] | ((unsigned)(myd[j] & 63) << 17);
            }
        }
    } else if (blockIdx.x < PART_BLOCKS + WPK_BLOCKS) {
        // ---- pack Wcat into B-fragment order (bf16) ----
        int kg  = (blockIdx.x - PART_BLOCKS) * 2 + (t >> 7);   // 0..31
        int col = t & 127;
        unsigned short v[8];
#pragma unroll
        for (int j = 0; j < 8; ++j) {
            int k = kg * 8 + j;
            const float* W = (k < 128) ? (Wself + (size_t)k * D)
                                       : (Wneigh + (size_t)(k - 128) * D);
            v[j] = f2bf(W[col]);
        }
        uint4 o;
        o.x = (unsigned)v[0] | ((unsigned)v[1] << 16);
        o.y = (unsigned)v[2] | ((unsigned)v[3] << 16);
        o.z = (unsigned)v[4] | ((unsigned)v[5] << 16);
        o.w = (unsigned)v[6] | ((unsigned)v[7] << 16);
        ((uint4*)Wp)[kg * 128 + col] = o;
    } else {
        // ---- h (fp32) -> hf8 (e4m3), pure streaming ----
        int i = (blockIdx.x - PART_BLOCKS - WPK_BLOCKS) * 256 + t;
        const float4* h4 = (const float4*)h;
        float4 a = h4[(size_t)i * 2];
        float4 b = h4[(size_t)i * 2 + 1];
        unsigned q0 = __builtin_amdgcn_cvt_pk_fp8_f32(a.x, a.y, 0u, false);
        q0          = __builtin_amdgcn_cvt_pk_fp8_f32(a.z, a.w, q0, true);
        unsigned q1 = __builtin_amdgcn_cvt_pk_fp8_f32(b.x, b.y, 0u, false);
        q1          = __builtin_amdgcn_cvt_pk_fp8_f32(b.z, b.w, q1, true);
        hf8[i] = make_uint2(q0, q1);
    }
}

// ---------------------------------------------------------------------------
// Fused per-bucket kernel, 512 threads:
//   Phase 0: self rows fp32 -> bf16 -> Xs cols 0..127.
//   Phase A: counting-sort the bucket's edges into LDS (by dst&63).
//   Phase B: fp8 gather — 64 groups of 8 lanes, one node each; lane loads
//            uint4 (16B, 16 features); 8-deep chains; floatx2 accumulate;
//            mean bf16 -> Xs cols 128..255.
//   Phase C: pure-LDS MFMA out[64x128] = Xs(64x256) @ Wcat, 8 waves.
// LDS 39.0KB; launch_bounds(512,6) caps VGPR ~85.
// ---------------------------------------------------------------------------
__global__ __launch_bounds__(512, 6) void k_agg_gemm(
    const float* __restrict__ h, const uint2* __restrict__ hf8,
    const int* __restrict__ bcursor, const unsigned* __restrict__ packed,
    const unsigned short* __restrict__ Wp, float* __restrict__ out)
{
    __shared__ unsigned short Xs[BK][XST];     // 33.0 KiB A-tile (bf16)
    __shared__ unsigned sorted[CAPB];          // 6 KiB
    __shared__ int cnt[BK], offs[BK], cur[BK];

    const int t      = threadIdx.x;
    const int bucket = blockIdx.x;
    const size_t ebeg = (size_t)bucket * CAPB;
    const int ecnt   = min(bcursor[(size_t)bucket * PADI], CAPB);

    if (t < BK) cnt[t] = 0;

    // ---- Phase 0: self rows fp32 -> bf16 into Xs cols 0..127 ----
    {
        int row = t >> 3, seg = t & 7;          // 64 rows x 8 segs of 16 floats
        int grow = min(bucket * BK + row, NN - 1);
        const float4* hp = (const float4*)(h + (size_t)grow * D + seg * 16);
        float4 f0 = hp[0], f1 = hp[1], f2 = hp[2], f3 = hp[3];
        uint4 q0, q1;
        q0.x = (unsigned)f2bf(f0.x) | ((unsigned)f2bf(f0.y) << 16);
        q0.y = (unsigned)f2bf(f0.z) | ((unsigned)f2bf(f0.w) << 16);
        q0.z = (unsigned)f2bf(f1.x) | ((unsigned)f2bf(f1.y) << 16);
        q0.w = (unsigned)f2bf(f1.z) | ((unsigned)f2bf(f1.w) << 16);
        q1.x = (unsigned)f2bf(f2.x) | ((unsigned)f2bf(f2.y) << 16);
        q1.y = (unsigned)f2bf(f2.z) | ((unsigned)f2bf(f2.w) << 16);
        q1.z = (unsigned)f2bf(f3.x) | ((unsigned)f2bf(f3.y) << 16);
        q1.w = (unsigned)f2bf(f3.z) | ((unsigned)f2bf(f3.w) << 16);
        *(uint4*)&Xs[row][seg * 16]     = q0;
        *(uint4*)&Xs[row][seg * 16 + 8] = q1;
    }
    __syncthreads();

    // ---- Phase A: counting sort of the bucket's edges into LDS ----
    unsigned pk[3];
#pragma unroll
    for (int i = 0; i < 3; ++i) {
        int idx = t + i * 512;
        pk[i] = (idx < ecnt) ? packed[ebeg + idx] : 0u;
    }
#pragma unroll
    for (int i = 0; i < 3; ++i) {
        int idx = t + i * 512;
        if (idx < ecnt) atomicAdd(&cnt[(pk[i] >> 17) & 63u], 1);
    }
    __syncthreads();
    if (t < BK) {                       // 64-wide shuffle scan (wave 0)
        int v = cnt[t];
        int sum = v;
#pragma unroll
        for (int off = 1; off < 64; off <<= 1) {
            int u = __shfl_up(sum, off, 64);
            if (t >= off) sum += u;
        }
        offs[t] = sum - v;
        cur[t]  = sum - v;
    }
    __syncthreads();
#pragma unroll
    for (int i = 0; i < 3; ++i) {
        int idx = t + i * 512;
        if (idx < ecnt) {
            int pos = atomicAdd(&cur[(pk[i] >> 17) & 63u], 1);
            sorted[pos] = pk[i] & 0x1FFFFu;
        }
    }
    __syncthreads();

    // ---- Phase B: fp8 gather, 8-lane groups, 8-deep, pk accumulate ----
    {
        const int g  = t >> 3;          // node 0..63 (one per group)
        const int l8 = t & 7;           // 16-feature slice
        const int beg = offs[g];
        const int n   = cnt[g];
        const uint4* __restrict__ hr = (const uint4*)hf8;   // 8 uint4 per row

        floatx2 ac[8];
#pragma unroll
        for (int j = 0; j < 8; ++j) ac[j] = (floatx2){0.f, 0.f};

#define ACC16(X) do {                                                         \
            unsigned ww0 = (X).x, ww1 = (X).y, ww2 = (X).z, ww3 = (X).w;      \
            ac[0] += __builtin_amdgcn_cvt_pk_f32_fp8(ww0, false);             \
            ac[1] += __builtin_amdgcn_cvt_pk_f32_fp8(ww0, true);              \
            ac[2] += __builtin_amdgcn_cvt_pk_f32_fp8(ww1, false);             \
            ac[3] += __builtin_amdgcn_cvt_pk_f32_fp8(ww1, true);              \
            ac[4] += __builtin_amdgcn_cvt_pk_f32_fp8(ww2, false);             \
            ac[5] += __builtin_amdgcn_cvt_pk_f32_fp8(ww2, true);              \
            ac[6] += __builtin_amdgcn_cvt_pk_f32_fp8(ww3, false);             \
            ac[7] += __builtin_amdgcn_cvt_pk_f32_fp8(ww3, true);              \
        } while (0)

        int e = 0;
        for (; e + 7 < n; e += 8) {
            uint4 x0 = hr[(size_t)sorted[beg + e]     * 8 + l8];
            uint4 x1 = hr[(size_t)sorted[beg + e + 1] * 8 + l8];
            uint4 x2 = hr[(size_t)sorted[beg + e + 2] * 8 + l8];
            uint4 x3 = hr[(size_t)sorted[beg + e + 3] * 8 + l8];
            uint4 x4 = hr[(size_t)sorted[beg + e + 4] * 8 + l8];
            uint4 x5 = hr[(size_t)sorted[beg + e + 5] * 8 + l8];
            uint4 x6 = hr[(size_t)sorted[beg + e + 6] * 8 + l8];
            uint4 x7 = hr[(size_t)sorted[beg + e + 7] * 8 + l8];
            ACC16(x0); ACC16(x1); ACC16(x2); ACC16(x3);
            ACC16(x4); ACC16(x5); ACC16(x6); ACC16(x7);
        }
        for (; e + 1 < n; e += 2) {
            uint4 x0 = hr[(size_t)sorted[beg + e]     * 8 + l8];
            uint4 x1 = hr[(size_t)sorted[beg + e + 1] * 8 + l8];
            ACC16(x0); ACC16(x1);
        }
        if (e < n) {
            uint4 x0 = hr[(size_t)sorted[beg + e] * 8 + l8];
            ACC16(x0);
        }
#undef ACC16

        float inv = (n > 0) ? 1.0f / (float)n : 0.0f;
        unsigned short m[16];
#pragma unroll
        for (int j = 0; j < 8; ++j) {
            m[j * 2]     = f2bf(ac[j].x * inv);
            m[j * 2 + 1] = f2bf(ac[j].y * inv);
        }
        uint4 o0, o1;
        o0.x = (unsigned)m[0]  | ((unsigned)m[1]  << 16);
        o0.y = (unsigned)m[2]  | ((unsigned)m[3]  << 16);
        o0.z = (unsigned)m[4]  | ((unsigned)m[5]  << 16);
        o0.w = (unsigned)m[6]  | ((unsigned)m[7]  << 16);
        o1.x = (unsigned)m[8]  | ((unsigned)m[9]  << 16);
        o1.y = (unsigned)m[10] | ((unsigned)m[11] << 16);
        o1.z = (unsigned)m[12] | ((unsigned)m[13] << 16);
        o1.w = (unsigned)m[14] | ((unsigned)m[15] << 16);
        *(uint4*)&Xs[g][128 + l8 * 16]     = o0;
        *(uint4*)&Xs[g][128 + l8 * 16 + 8] = o1;
    }
    __syncthreads();

    // ---- Phase C: MFMA  out[64x128] = Xs(64x256) @ Wcat(256x128), 8 waves -
    const int wave  = t >> 6;            // 0..7
    const int lane  = t & 63;
    const int wl16  = lane & 15;
    const int kg4   = lane >> 4;         // 0..3
    const int wrow  = wave & 3;          // row-group 0..3
    const int chalf = wave >> 2;         // col half 0/1
    floatx4 acc[4];
#pragma unroll
    for (int c = 0; c < 4; ++c) acc[c] = (floatx4){0.f, 0.f, 0.f, 0.f};

    const int arow = wrow * 16 + wl16;   // 0..63
#pragma unroll
    for (int ks = 0; ks < 8; ++ks) {
        const short8 a = *(const short8*)&Xs[arow][ks * 32 + kg4 * 8];
#pragma unroll
        for (int c = 0; c < 4; ++c) {
            const int ct = chalf * 4 + c;
            const short8 b = *(const short8*)(Wp + (((ks * 4 + kg4) * 128) + ct * 16 + wl16) * 8);
            acc[c] = __builtin_amdgcn_mfma_f32_16x16x32_bf16(a, b, acc[c], 0, 0, 0);
        }
    }

    // C/D layout: col = lane&15, row = (lane>>4)*4 + reg
    const int rbase = bucket * BK + wrow * 16 + kg4 * 4;
#pragma unroll
    for (int r = 0; r < 4; ++r) {
        int row = rbase + r;
        if (row < NN) {
            float* o = out + (size_t)row * D + chalf * 64 + wl16;
#pragma unroll
            for (int c = 0; c < 4; ++c)
                o[c * 16] = acc[c][r];
        }
    }
}

extern "C" void kernel_launch(void* const* d_in, const int* in_sizes, int n_in,
                              void* d_out, int out_size, void* d_ws, size_t ws_size,
                              hipStream_t stream) {
    const float* h      = (const float*)d_in[0];
    const int*   src    = (const int*)d_in[1];
    const int*   dst    = (const int*)d_in[2];
    const float* Wself  = (const float*)d_in[3];
    const float* Wneigh = (const float*)d_in[4];
    float*       out    = (float*)d_out;

    // workspace layout (~23 MB)
    uint2* hf8         = (uint2*)d_ws;                         // NN*D/8 uint2 (12.8MB)
    unsigned short* Wp = (unsigned short*)(hf8 + (size_t)NN * D / 8);  // 64KB
    unsigned* packed   = (unsigned*)(Wp + 256 * D);            // NB*CAPB (9.6MB)
    uintptr_t bc_a     = ((uintptr_t)(packed + (size_t)NB * CAPB) + 255) & ~(uintptr_t)255;
    int* bcursor       = (int*)bc_a;                           // NB*PADI (200KB, padded)

    hipMemsetAsync(bcursor, 0, (size_t)NB * PADI * sizeof(int), stream);

    k_prep     <<<dim3(PART_BLOCKS + WPK_BLOCKS + CVT_BLOCKS), 256, 0, stream>>>(
                   h, Wself, Wneigh, src, dst, hf8, Wp, bcursor, packed);
    k_agg_gemm <<<dim3(NB), 512, 0, stream>>>(h, hf8, bcursor, packed, Wp, out);
}

// Round 6
// 185.085 us; speedup vs baseline: 1.7002x; 1.7002x over previous
//
#include <hip/hip_runtime.h>

// SAGEConv — fp8-gather + fused aggregate/GEMM, fixed-capacity buckets.
// R12 post-mortem: REGRESSION 62->197us. WRITE 50->359MB, FETCH 105->326MB
// = scratch spill of the 8-deep uint4 load batch (32 VGPR loads + 16 acc
// exceeded what hipcc would allocate under launch_bounds(512,6); it clamped
// to 40 and spilled every gathered row through scratch). hbm_gbps 3.5TB/s
// of pure garbage traffic. R13: same Phase-B structure (8-lane groups,
// full-128B-row uint4 loads) but (a) 4-deep unroll -> ~40 live VGPRs
// (R11 proved fits), (b) __launch_bounds__(512) with NO min-waves hint so
// the allocator picks a no-spill count. Predict WRITE ~50MB, FETCH ~105MB,
// k_agg ~45us, total ~165; k_prep becomes visible in top-5 -> R14 target.

constexpr int NN = 100000;
constexpr int NE = 1600000;
constexpr int D  = 128;
constexpr int BK = 64;                      // nodes per bucket
constexpr int NB = (NN + BK - 1) / BK;      // 1563 buckets
constexpr int PB = 8192;                    // edges per partition block
constexpr int CAPB = 1536;                  // fixed bucket capacity (mean 1024, sd 32)
constexpr int XST = 258;                    // Xs row stride (shorts): 516B -> +1-pad
constexpr int PADI = 32;                    // ints per bucket counter slot (128B line)
constexpr int PART_BLOCKS = (NE + PB - 1) / PB;   // 196
constexpr int WPK_BLOCKS  = 16;
constexpr int CVT_BLOCKS  = NN * D / 8 / 256;     // 6250

typedef __attribute__((ext_vector_type(8))) short short8;   // 8 bf16 (4 VGPR)
typedef __attribute__((ext_vector_type(4))) float floatx4;  // MFMA C/D
typedef __attribute__((ext_vector_type(2))) float floatx2;

static __device__ __forceinline__ unsigned short f2bf(float f) {
    unsigned u = __float_as_uint(f);
    unsigned r = ((u >> 16) & 1u) + 0x7fffu;
    return (unsigned short)((u + r) >> 16);
}

// ---------------------------------------------------------------------------
// Fused prep: blocks [0,196) partition edges; [196,212) pack Wcat;
// [212,6462) h fp32 -> fp8. Part blocks first (long pole starts first).
// ---------------------------------------------------------------------------
__global__ __launch_bounds__(256) void k_prep(
    const float* __restrict__ h, const float* __restrict__ Wself,
    const float* __restrict__ Wneigh, const int* __restrict__ src,
    const int* __restrict__ dst, uint2* __restrict__ hf8,
    unsigned short* __restrict__ Wp, int* __restrict__ bcursor,
    unsigned* __restrict__ packed)
{
    const int t = threadIdx.x;
    if (blockIdx.x < PART_BLOCKS) {
        // ---- edge partition into fixed-capacity buckets ----
        __shared__ int lh[NB];
        const int e0 = blockIdx.x * PB;
        for (int i = t; i < NB; i += 256) lh[i] = 0;
        __syncthreads();

        int myd[32], msrc[32];
#pragma unroll
        for (int j = 0; j < 32; ++j) {
            int e = e0 + j * 256 + t;
            myd[j] = (e < NE) ? dst[e] : -1;
        }
#pragma unroll
        for (int j = 0; j < 32; ++j) {
            int e = e0 + j * 256 + t;
            msrc[j] = (e < NE) ? src[e] : 0;
        }
#pragma unroll
        for (int j = 0; j < 32; ++j)
            if (myd[j] >= 0) atomicAdd(&lh[myd[j] >> 6], 1);
        __syncthreads();
        for (int i = t; i < NB; i += 256) {
            int c = lh[i];
            if (c) lh[i] = atomicAdd(&bcursor[(size_t)i * PADI], c);
        }
        __syncthreads();
#pragma unroll
        for (int j = 0; j < 32; ++j) {
            if (myd[j] >= 0) {
                int b = myd[j] >> 6;
                int pos = atomicAdd(&lh[b], 1);        // within-bucket rank
                if (pos < CAPB)
                    packed[(size_t)b * CAPB + pos] =
                        (unsigned)msrc[j] | ((unsigned)(myd[j] & 63) << 17);
            }
        }
    } else if (blockIdx.x < PART_BLOCKS + WPK_BLOCKS) {
        // ---- pack Wcat into B-fragment order (bf16) ----
        int kg  = (blockIdx.x - PART_BLOCKS) * 2 + (t >> 7);   // 0..31
        int col = t & 127;
        unsigned short v[8];
#pragma unroll
        for (int j = 0; j < 8; ++j) {
            int k = kg * 8 + j;
            const float* W = (k < 128) ? (Wself + (size_t)k * D)
                                       : (Wneigh + (size_t)(k - 128) * D);
            v[j] = f2bf(W[col]);
        }
        uint4 o;
        o.x = (unsigned)v[0] | ((unsigned)v[1] << 16);
        o.y = (unsigned)v[2] | ((unsigned)v[3] << 16);
        o.z = (unsigned)v[4] | ((unsigned)v[5] << 16);
        o.w = (unsigned)v[6] | ((unsigned)v[7] << 16);
        ((uint4*)Wp)[kg * 128 + col] = o;
    } else {
        // ---- h (fp32) -> hf8 (e4m3), pure streaming ----
        int i = (blockIdx.x - PART_BLOCKS - WPK_BLOCKS) * 256 + t;
        const float4* h4 = (const float4*)h;
        float4 a = h4[(size_t)i * 2];
        float4 b = h4[(size_t)i * 2 + 1];
        unsigned q0 = __builtin_amdgcn_cvt_pk_fp8_f32(a.x, a.y, 0u, false);
        q0          = __builtin_amdgcn_cvt_pk_fp8_f32(a.z, a.w, q0, true);
        unsigned q1 = __builtin_amdgcn_cvt_pk_fp8_f32(b.x, b.y, 0u, false);
        q1          = __builtin_amdgcn_cvt_pk_fp8_f32(b.z, b.w, q1, true);
        hf8[i] = make_uint2(q0, q1);
    }
}

// ---------------------------------------------------------------------------
// Fused per-bucket kernel, 512 threads:
//   Phase 0: self rows fp32 -> bf16 -> Xs cols 0..127.
//   Phase A: counting-sort the bucket's edges into LDS (by dst&63).
//   Phase B: fp8 gather — 64 groups of 8 lanes, one node each; lane loads
//            uint4 (16B, 16 features); 4-deep chains (no spill);
//            floatx2 accumulate; mean bf16 -> Xs cols 128..255.
//   Phase C: pure-LDS MFMA out[64x128] = Xs(64x256) @ Wcat, 8 waves.
// LDS 39.0KB; no min-waves hint (avoid forced spill — R12 lesson).
// ---------------------------------------------------------------------------
__global__ __launch_bounds__(512) void k_agg_gemm(
    const float* __restrict__ h, const uint2* __restrict__ hf8,
    const int* __restrict__ bcursor, const unsigned* __restrict__ packed,
    const unsigned short* __restrict__ Wp, float* __restrict__ out)
{
    __shared__ unsigned short Xs[BK][XST];     // 33.0 KiB A-tile (bf16)
    __shared__ unsigned sorted[CAPB];          // 6 KiB
    __shared__ int cnt[BK], offs[BK], cur[BK];

    const int t      = threadIdx.x;
    const int bucket = blockIdx.x;
    const size_t ebeg = (size_t)bucket * CAPB;
    const int ecnt   = min(bcursor[(size_t)bucket * PADI], CAPB);

    if (t < BK) cnt[t] = 0;

    // ---- Phase 0: self rows fp32 -> bf16 into Xs cols 0..127 ----
    {
        int row = t >> 3, seg = t & 7;          // 64 rows x 8 segs of 16 floats
        int grow = min(bucket * BK + row, NN - 1);
        const float4* hp = (const float4*)(h + (size_t)grow * D + seg * 16);
        float4 f0 = hp[0], f1 = hp[1], f2 = hp[2], f3 = hp[3];
        uint4 q0, q1;
        q0.x = (unsigned)f2bf(f0.x) | ((unsigned)f2bf(f0.y) << 16);
        q0.y = (unsigned)f2bf(f0.z) | ((unsigned)f2bf(f0.w) << 16);
        q0.z = (unsigned)f2bf(f1.x) | ((unsigned)f2bf(f1.y) << 16);
        q0.w = (unsigned)f2bf(f1.z) | ((unsigned)f2bf(f1.w) << 16);
        q1.x = (unsigned)f2bf(f2.x) | ((unsigned)f2bf(f2.y) << 16);
        q1.y = (unsigned)f2bf(f2.z) | ((unsigned)f2bf(f2.w) << 16);
        q1.z = (unsigned)f2bf(f3.x) | ((unsigned)f2bf(f3.y) << 16);
        q1.w = (unsigned)f2bf(f3.z) | ((unsigned)f2bf(f3.w) << 16);
        *(uint4*)&Xs[row][seg * 16]     = q0;
        *(uint4*)&Xs[row][seg * 16 + 8] = q1;
    }
    __syncthreads();

    // ---- Phase A: counting sort of the bucket's edges into LDS ----
    unsigned pk[3];
#pragma unroll
    for (int i = 0; i < 3; ++i) {
        int idx = t + i * 512;
        pk[i] = (idx < ecnt) ? packed[ebeg + idx] : 0u;
    }
#pragma unroll
    for (int i = 0; i < 3; ++i) {
        int idx = t + i * 512;
        if (idx < ecnt) atomicAdd(&cnt[(pk[i] >> 17) & 63u], 1);
    }
    __syncthreads();
    if (t < BK) {                       // 64-wide shuffle scan (wave 0)
        int v = cnt[t];
        int sum = v;
#pragma unroll
        for (int off = 1; off < 64; off <<= 1) {
            int u = __shfl_up(sum, off, 64);
            if (t >= off) sum += u;
        }
        offs[t] = sum - v;
        cur[t]  = sum - v;
    }
    __syncthreads();
#pragma unroll
    for (int i = 0; i < 3; ++i) {
        int idx = t + i * 512;
        if (idx < ecnt) {
            int pos = atomicAdd(&cur[(pk[i] >> 17) & 63u], 1);
            sorted[pos] = pk[i] & 0x1FFFFu;
        }
    }
    __syncthreads();

    // ---- Phase B: fp8 gather, 8-lane groups, 4-deep, pk accumulate ----
    {
        const int g  = t >> 3;          // node 0..63 (one per group)
        const int l8 = t & 7;           // 16-feature slice
        const int beg = offs[g];
        const int n   = cnt[g];
        const uint4* __restrict__ hr = (const uint4*)hf8;   // 8 uint4 per row

        floatx2 ac[8];
#pragma unroll
        for (int j = 0; j < 8; ++j) ac[j] = (floatx2){0.f, 0.f};

#define ACC16(X) do {                                                         \
            unsigned ww0 = (X).x, ww1 = (X).y, ww2 = (X).z, ww3 = (X).w;      \
            ac[0] += __builtin_amdgcn_cvt_pk_f32_fp8(ww0, false);             \
            ac[1] += __builtin_amdgcn_cvt_pk_f32_fp8(ww0, true);              \
            ac[2] += __builtin_amdgcn_cvt_pk_f32_fp8(ww1, false);             \
            ac[3] += __builtin_amdgcn_cvt_pk_f32_fp8(ww1, true);              \
            ac[4] += __builtin_amdgcn_cvt_pk_f32_fp8(ww2, false);             \
            ac[5] += __builtin_amdgcn_cvt_pk_f32_fp8(ww2, true);              \
            ac[6] += __builtin_amdgcn_cvt_pk_f32_fp8(ww3, false);             \
            ac[7] += __builtin_amdgcn_cvt_pk_f32_fp8(ww3, true);              \
        } while (0)

        int e = 0;
        for (; e + 3 < n; e += 4) {
            uint4 x0 = hr[(size_t)sorted[beg + e]     * 8 + l8];
            uint4 x1 = hr[(size_t)sorted[beg + e + 1] * 8 + l8];
            uint4 x2 = hr[(size_t)sorted[beg + e + 2] * 8 + l8];
            uint4 x3 = hr[(size_t)sorted[beg + e + 3] * 8 + l8];
            ACC16(x0); ACC16(x1); ACC16(x2); ACC16(x3);
        }
        for (; e + 1 < n; e += 2) {
            uint4 x0 = hr[(size_t)sorted[beg + e]     * 8 + l8];
            uint4 x1 = hr[(size_t)sorted[beg + e + 1] * 8 + l8];
            ACC16(x0); ACC16(x1);
        }
        if (e < n) {
            uint4 x0 = hr[(size_t)sorted[beg + e] * 8 + l8];
            ACC16(x0);
        }
#undef ACC16

        float inv = (n > 0) ? 1.0f / (float)n : 0.0f;
        unsigned short m[16];
#pragma unroll
        for (int j = 0; j < 8; ++j) {
            m[j * 2]     = f2bf(ac[j].x * inv);
            m[j * 2 + 1] = f2bf(ac[j].y * inv);
        }
        uint4 o0, o1;
        o0.x = (unsigned)m[0]  | ((unsigned)m[1]  << 16);
        o0.y = (unsigned)m[2]  | ((unsigned)m[3]  << 16);
        o0.z = (unsigned)m[4]  | ((unsigned)m[5]  << 16);
        o0.w = (unsigned)m[6]  | ((unsigned)m[7]  << 16);
        o1.x = (unsigned)m[8]  | ((unsigned)m[9]  << 16);
        o1.y = (unsigned)m[10] | ((unsigned)m[11] << 16);
        o1.z = (unsigned)m[12] | ((unsigned)m[13] << 16);
        o1.w = (unsigned)m[14] | ((unsigned)m[15] << 16);
        *(uint4*)&Xs[g][128 + l8 * 16]     = o0;
        *(uint4*)&Xs[g][128 + l8 * 16 + 8] = o1;
    }
    __syncthreads();

    // ---- Phase C: MFMA  out[64x128] = Xs(64x256) @ Wcat(256x128), 8 waves -
    const int wave  = t >> 6;            // 0..7
    const int lane  = t & 63;
    const int wl16  = lane & 15;
    const int kg4   = lane >> 4;         // 0..3
    const int wrow  = wave & 3;          // row-group 0..3
    const int chalf = wave >> 2;         // col half 0/1
    floatx4 acc[4];
#pragma unroll
    for (int c = 0; c < 4; ++c) acc[c] = (floatx4){0.f, 0.f, 0.f, 0.f};

    const int arow = wrow * 16 + wl16;   // 0..63
#pragma unroll
    for (int ks = 0; ks < 8; ++ks) {
        const short8 a = *(const short8*)&Xs[arow][ks * 32 + kg4 * 8];
#pragma unroll
        for (int c = 0; c < 4; ++c) {
            const int ct = chalf * 4 + c;
            const short8 b = *(const short8*)(Wp + (((ks * 4 + kg4) * 128) + ct * 16 + wl16) * 8);
            acc[c] = __builtin_amdgcn_mfma_f32_16x16x32_bf16(a, b, acc[c], 0, 0, 0);
        }
    }

    // C/D layout: col = lane&15, row = (lane>>4)*4 + reg
    const int rbase = bucket * BK + wrow * 16 + kg4 * 4;
#pragma unroll
    for (int r = 0; r < 4; ++r) {
        int row = rbase + r;
        if (row < NN) {
            float* o = out + (size_t)row * D + chalf * 64 + wl16;
#pragma unroll
            for (int c = 0; c < 4; ++c)
                o[c * 16] = acc[c][r];
        }
    }
}

extern "C" void kernel_launch(void* const* d_in, const int* in_sizes, int n_in,
                              void* d_out, int out_size, void* d_ws, size_t ws_size,
                              hipStream_t stream) {
    const float* h      = (const float*)d_in[0];
    const int*   src    = (const int*)d_in[1];
    const int*   dst    = (const int*)d_in[2];
    const float* Wself  = (const float*)d_in[3];
    const float* Wneigh = (const float*)d_in[4];
    float*       out    = (float*)d_out;

    // workspace layout (~23 MB)
    uint2* hf8         = (uint2*)d_ws;                         // NN*D/8 uint2 (12.8MB)
    unsigned short* Wp = (unsigned short*)(hf8 + (size_t)NN * D / 8);  // 64KB
    unsigned* packed   = (unsigned*)(Wp + 256 * D);            // NB*CAPB (9.6MB)
    uintptr_t bc_a     = ((uintptr_t)(packed + (size_t)NB * CAPB) + 255) & ~(uintptr_t)255;
    int* bcursor       = (int*)bc_a;                           // NB*PADI (200KB, padded)

    hipMemsetAsync(bcursor, 0, (size_t)NB * PADI * sizeof(int), stream);

    k_prep     <<<dim3(PART_BLOCKS + WPK_BLOCKS + CVT_BLOCKS), 256, 0, stream>>>(
                   h, Wself, Wneigh, src, dst, hf8, Wp, bcursor, packed);
    k_agg_gemm <<<dim3(NB), 512, 0, stream>>>(h, hf8, bcursor, packed, Wp, out);
}